// Round 2
// baseline (771.851 us; speedup 1.0000x reference)
//
#include <hip/hip_runtime.h>
#include <stdint.h>

#define B_ 16
#define T_ 4096
#define C_ 64
#define H_ 128
#define BQ 128
#define BK 64
#define KLS 136   // K LDS row stride (128 + 8 pad -> 4-bank row shift, 2-way = free)
#define VS  72    // Vt / P LDS row stride (64 + 8 pad)

typedef __attribute__((ext_vector_type(8))) short  short8;   // 8 bf16 = 4 VGPRs
typedef __attribute__((ext_vector_type(4))) float  floatx4;  // MFMA C/D frag

__device__ __forceinline__ unsigned short f2bf(float f) {
    union { float f; unsigned int u; } v; v.f = f;
    return (unsigned short)((v.u + 0x7fffu + ((v.u >> 16) & 1u)) >> 16);  // RNE
}

__device__ __forceinline__ float fexp2(float x) {
#if __has_builtin(__builtin_amdgcn_exp2f)
    return __builtin_amdgcn_exp2f(x);
#else
    return exp2f(x);
#endif
}

// ---------------------------------------------------------------------------
// Projections: q,k -> bf16 [B][T][H] row-major; v -> bf16 vt[B][H][T] (transposed)
// fp32 VALU compute (more accurate than bf16 MFMA for the tiny K=64 GEMM).
// ---------------------------------------------------------------------------
__global__ __launch_bounds__(256) void proj_kernel(
    const float* __restrict__ x, const float* __restrict__ Wk,
    const float* __restrict__ Wq, const float* __restrict__ Wv,
    unsigned short* __restrict__ qo, unsigned short* __restrict__ ko,
    unsigned short* __restrict__ vto)
{
    __shared__ __align__(16) char smem[48 * 1024];
    float* xl = (float*)smem;                                  // [64][64] fp32 x tile
    float* wl = (float*)(smem + 16384);                        // [64][128] fp32 W
    unsigned short* vtl = (unsigned short*)(smem + 16384);     // [128][72] bf16 (aliases wl)

    const int tid = threadIdx.x;
    const int b   = blockIdx.x >> 6;
    const int t0  = (blockIdx.x & 63) * 64;

    // stage x tile (coalesced float4)
    #pragma unroll
    for (int it = 0; it < 4; ++it) {
        int r = (tid >> 4) + it * 16;
        int c = (tid & 15) * 4;
        *(float4*)&xl[r * 64 + c] =
            *(const float4*)(x + ((size_t)(b * T_ + t0 + r)) * C_ + c);
    }

    const int h0 = (tid & 31) * 4;  // 4 consecutive head cols
    const int rg = tid >> 5;        // 8 row-groups of 8 rows

    for (int m = 0; m < 3; ++m) {
        const float* W = (m == 0) ? Wk : (m == 1) ? Wq : Wv;
        __syncthreads();
        #pragma unroll
        for (int it = 0; it < 8; ++it) {
            int r = (tid >> 5) + it * 8;
            int c = (tid & 31) * 4;
            *(float4*)&wl[r * 128 + c] = *(const float4*)(W + r * 128 + c);
        }
        __syncthreads();

        float acc[8][4];
        #pragma unroll
        for (int i = 0; i < 8; ++i)
            #pragma unroll
            for (int j = 0; j < 4; ++j) acc[i][j] = 0.f;

        #pragma unroll 8
        for (int c = 0; c < 64; ++c) {
            float4 w = *(const float4*)&wl[c * 128 + h0];
            #pragma unroll
            for (int i = 0; i < 8; ++i) {
                float xi = xl[(rg * 8 + i) * 64 + c];   // LDS broadcast (2-way = free)
                acc[i][0] += xi * w.x;
                acc[i][1] += xi * w.y;
                acc[i][2] += xi * w.z;
                acc[i][3] += xi * w.w;
            }
        }

        if (m < 2) {
            unsigned short* o = (m == 0) ? ko : qo;
            #pragma unroll
            for (int i = 0; i < 8; ++i) {
                ushort4 pk;
                pk.x = f2bf(acc[i][0]); pk.y = f2bf(acc[i][1]);
                pk.z = f2bf(acc[i][2]); pk.w = f2bf(acc[i][3]);
                *(ushort4*)(o + ((size_t)(b * T_ + t0 + rg * 8 + i)) * H_ + h0) = pk;
            }
        } else {
            __syncthreads();  // all waves done reading wl before aliasing it
            #pragma unroll
            for (int i = 0; i < 8; ++i)
                #pragma unroll
                for (int c2 = 0; c2 < 4; ++c2)
                    vtl[(h0 + c2) * VS + rg * 8 + i] = f2bf(acc[i][c2]);
            __syncthreads();
            int h  = tid >> 1;
            int sg = (tid & 1) * 32;
            int4* dst = (int4*)(vto + ((size_t)(b * H_ + h)) * T_ + t0 + sg);
            const int4* src = (const int4*)&vtl[h * VS + sg];
            dst[0] = src[0]; dst[1] = src[1]; dst[2] = src[2]; dst[3] = src[3];
        }
    }
}

// ---------------------------------------------------------------------------
// Flash attention, no-max softmax (logits bounded, exp2 can't overflow fp32).
// Block = 256 thr (4 waves), BQ=128 rows (wave owns 32 = 2 m-tiles), BK=64.
// s-split across blockIdx.z: each block covers T_/nsplit keys, writes
// UNNORMALIZED O partial + per-row sum; combine_kernel merges/normalizes.
// LDS (36864 B -> 4 blocks/CU): P scratch ALIASES the K region (extra barrier
// after QK guarantees K reads are done). Next chunk's K/Vt are prefetched to
// VGPRs during compute so global latency is hidden.
// mfma_f32_16x16x32_bf16: A[m=lane&15][k=quad*8+j], C/D col=lane&15,row=quad*4+reg.
// ---------------------------------------------------------------------------
__global__ __launch_bounds__(256, 4) void attn_kernel(
    const unsigned short* __restrict__ q,
    const unsigned short* __restrict__ k,
    const unsigned short* __restrict__ vt,
    float* __restrict__ O0, float* __restrict__ O1,
    float* __restrict__ Ls, int nsplit)
{
    __shared__ unsigned short sm[18432];           // 36864 B total
    unsigned short* Kl  = sm;                      // [64][KLS]  (8704 shorts)
    unsigned short* Vtl = sm + 9216;               // [128][VS]  (9216 shorts)
    // P scratch aliases [0, 9216) — safe: only live between barrier(3) and
    // the next chunk's barrier(1).

    const int tid  = threadIdx.x;
    const int wave = tid >> 6;
    const int lane = tid & 63;
    const int col  = lane & 15;   // n-index inside a 16-tile
    const int quad = lane >> 4;   // 0..3
    const int b    = blockIdx.y;
    const int q0   = blockIdx.x * BQ;
    const int split  = blockIdx.z;
    const int NC     = T_ / BK / nsplit;           // chunks this block handles
    const int s_base = split * (T_ / nsplit);

    // Q A-fragments straight from global (read once, reused NC chunks)
    short8 qf[2][4];
    #pragma unroll
    for (int mt = 0; mt < 2; ++mt) {
        const unsigned short* qrow =
            q + ((size_t)(b * T_ + q0 + wave * 32 + mt * 16 + col)) * H_ + quad * 8;
        #pragma unroll
        for (int ks = 0; ks < 4; ++ks)
            qf[mt][ks] = *(const short8*)(qrow + ks * 32);
    }

    floatx4 o[2][8];              // O accum [mt][ht 16-wide tiles]
    #pragma unroll
    for (int mt = 0; mt < 2; ++mt)
        #pragma unroll
        for (int ht = 0; ht < 8; ++ht) { o[mt][ht][0]=0.f; o[mt][ht][1]=0.f; o[mt][ht][2]=0.f; o[mt][ht][3]=0.f; }
    float lsum[2][4] = {{0.f,0.f,0.f,0.f},{0.f,0.f,0.f,0.f}};   // softmax denom partials

    const float SC = 0.125f * 1.44269504088896340736f;  // scale * log2(e)
    unsigned short* Pw = sm + wave * 32 * VS;            // per-wave P slice (aliases Kl)

    // prefetch registers for staging
    int4 kr[4], vr[4];
    #define PREFETCH(S0)                                                          \
        do {                                                                      \
            _Pragma("unroll")                                                     \
            for (int it = 0; it < 4; ++it)                                        \
                kr[it] = *(const int4*)(k + ((size_t)(b * T_ + (S0) + (tid >> 4) + it * 16)) * H_ + (tid & 15) * 8); \
            _Pragma("unroll")                                                     \
            for (int it = 0; it < 4; ++it)                                        \
                vr[it] = *(const int4*)(vt + ((size_t)(b * H_ + (tid >> 3) + it * 32)) * T_ + (S0) + (tid & 7) * 8); \
        } while (0)

    PREFETCH(s_base);

    for (int ci = 0; ci < NC; ++ci) {
        __syncthreads();   // (1) prior chunk's K/Vt/P reads complete
        #pragma unroll
        for (int it = 0; it < 4; ++it)
            *(int4*)&Kl[((tid >> 4) + it * 16) * KLS + (tid & 15) * 8] = kr[it];
        #pragma unroll
        for (int it = 0; it < 4; ++it)
            *(int4*)&Vtl[((tid >> 3) + it * 32) * VS + (tid & 7) * 8] = vr[it];
        __syncthreads();   // (2) staging visible

        if (ci + 1 < NC) PREFETCH(s_base + (ci + 1) * BK);  // latency hidden by compute

        // S = Q K^T : per wave 2 m-tiles x 4 n-tiles, K=128 in 4 steps
        floatx4 s[2][4];
        #pragma unroll
        for (int mt = 0; mt < 2; ++mt)
            #pragma unroll
            for (int nt = 0; nt < 4; ++nt) { s[mt][nt][0]=0.f; s[mt][nt][1]=0.f; s[mt][nt][2]=0.f; s[mt][nt][3]=0.f; }
        #pragma unroll
        for (int ks = 0; ks < 4; ++ks) {
            #pragma unroll
            for (int nt = 0; nt < 4; ++nt) {
                short8 kf = *(const short8*)&Kl[(nt * 16 + col) * KLS + ks * 32 + quad * 8];
                s[0][nt] = __builtin_amdgcn_mfma_f32_16x16x32_bf16(qf[0][ks], kf, s[0][nt], 0, 0, 0);
                s[1][nt] = __builtin_amdgcn_mfma_f32_16x16x32_bf16(qf[1][ks], kf, s[1][nt], 0, 0, 0);
            }
        }

        __syncthreads();   // (3) all K reads done -> safe to write P over K region

        // P = exp2(S * SC); accumulate row-sum partials; C-layout -> LDS (A-layout readback)
        #pragma unroll
        for (int mt = 0; mt < 2; ++mt)
            #pragma unroll
            for (int nt = 0; nt < 4; ++nt)
                #pragma unroll
                for (int r = 0; r < 4; ++r) {
                    float p = fexp2(s[mt][nt][r] * SC);
                    lsum[mt][r] += p;
                    Pw[(mt * 16 + quad * 4 + r) * VS + nt * 16 + col] = f2bf(p);
                }

        // O += P V  (same-wave LDS write->read: DS pipe is in-order per wave)
        #pragma unroll
        for (int ks = 0; ks < 2; ++ks) {
            short8 pf0 = *(const short8*)&Pw[(0 * 16 + col) * VS + ks * 32 + quad * 8];
            short8 pf1 = *(const short8*)&Pw[(1 * 16 + col) * VS + ks * 32 + quad * 8];
            #pragma unroll
            for (int ht = 0; ht < 8; ++ht) {
                short8 vf = *(const short8*)&Vtl[(ht * 16 + col) * VS + ks * 32 + quad * 8];
                o[0][ht] = __builtin_amdgcn_mfma_f32_16x16x32_bf16(pf0, vf, o[0][ht], 0, 0, 0);
                o[1][ht] = __builtin_amdgcn_mfma_f32_16x16x32_bf16(pf1, vf, o[1][ht], 0, 0, 0);
            }
        }
    }
    #undef PREFETCH

    // epilogue: reduce denom across the 16 cols, store UNNORMALIZED O + lsum
    float* Op = (split == 0) ? O0 : O1;
    #pragma unroll
    for (int mt = 0; mt < 2; ++mt)
        #pragma unroll
        for (int r = 0; r < 4; ++r) {
            float l = lsum[mt][r];
            l += __shfl_xor(l, 1);
            l += __shfl_xor(l, 2);
            l += __shfl_xor(l, 4);
            l += __shfl_xor(l, 8);
            int row = q0 + wave * 32 + mt * 16 + quad * 4 + r;
            if (col == 0)
                Ls[(size_t)split * (B_ * T_) + b * T_ + row] = l;
            float* orow = Op + ((size_t)(b * T_ + row)) * H_;
            #pragma unroll
            for (int ht = 0; ht < 8; ++ht)
                orow[ht * 16 + col] = o[mt][ht][r];
        }
}

// ---------------------------------------------------------------------------
// Merge s-split partials and normalize: out = (O0 [+ O1]) / (l0 [+ l1])
// ---------------------------------------------------------------------------
__global__ __launch_bounds__(256) void combine_kernel(
    float* __restrict__ out, const float* __restrict__ O1,
    const float* __restrict__ Ls, int nsplit)
{
    int i = blockIdx.x * 256 + threadIdx.x;   // float4 index, H/4 = 32 per row
    int row = i >> 5;
    float4 a = ((const float4*)out)[i];
    float l = Ls[row];
    if (nsplit == 2) {
        float4 c = ((const float4*)O1)[i];
        a.x += c.x; a.y += c.y; a.z += c.z; a.w += c.w;
        l += Ls[B_ * T_ + row];
    }
    float rinv = 1.0f / l;
    a.x *= rinv; a.y *= rinv; a.z *= rinv; a.w *= rinv;
    ((float4*)out)[i] = a;
}

extern "C" void kernel_launch(void* const* d_in, const int* in_sizes, int n_in,
                              void* d_out, int out_size, void* d_ws, size_t ws_size,
                              hipStream_t stream)
{
    const float* x  = (const float*)d_in[0];
    const float* Wk = (const float*)d_in[1];
    const float* Wq = (const float*)d_in[2];
    const float* Wv = (const float*)d_in[3];
    float* out = (float*)d_out;

    const size_t elems = (size_t)B_ * T_ * H_;            // 8.4M elements
    unsigned short* qb  = (unsigned short*)d_ws;          // bf16 q   [B][T][H]  16 MB
    unsigned short* kb  = qb + elems;                     // bf16 k   [B][T][H]  16 MB
    unsigned short* vtb = kb + elems;                     // bf16 v^T [B][H][T]  16 MB
    float* Ls = (float*)(vtb + elems);                    // [2][B*T] fp32 row sums
    float* O1 = Ls + 2 * (size_t)B_ * T_;                 // split-1 O partial (fp32, 32 MB)

    const size_t need2 = 3 * elems * 2 + 2 * (size_t)B_ * T_ * 4 + elems * 4;
    const int ns = (ws_size >= need2) ? 2 : 1;

    proj_kernel<<<dim3(B_ * 64), dim3(256), 0, stream>>>(x, Wk, Wq, Wv, qb, kb, vtb);
    attn_kernel<<<dim3(T_ / BQ, B_, ns), dim3(256), 0, stream>>>(qb, kb, vtb, out, O1, Ls, ns);
    combine_kernel<<<dim3((int)(elems / 4 / 256)), dim3(256), 0, stream>>>(out, O1, Ls, ns);
}

// Round 3
// 364.006 us; speedup vs baseline: 2.1204x; 2.1204x over previous
//
#include <hip/hip_runtime.h>
#include <hip/hip_bf16.h>
#include <stdint.h>

#define B_ 16
#define T_ 4096
#define C_ 64
#define H_ 128
#define BQ 128
#define BK 64
#define KLS 136   // K LDS row stride in shorts (272 B = 16-aligned, 2-way bank alias = free)
#define VS  72    // proj vt-transpose scratch stride

typedef __attribute__((ext_vector_type(8))) short  short8;   // 8 bf16 = 4 VGPRs
typedef __attribute__((ext_vector_type(4))) float  floatx4;  // MFMA C/D frag

__device__ __forceinline__ unsigned short f2bf(float f) {
    union { float f; unsigned int u; } v; v.f = f;
    return (unsigned short)((v.u + 0x7fffu + ((v.u >> 16) & 1u)) >> 16);  // RNE
}

__device__ __forceinline__ unsigned pk2bf(float a, float b) {   // low=a, high=b
    union { __hip_bfloat162 h; unsigned u; } v;
    v.h = __float22bfloat162_rn(float2{a, b});
    return v.u;
}

__device__ __forceinline__ float fexp2(float x) {
#if __has_builtin(__builtin_amdgcn_exp2f)
    return __builtin_amdgcn_exp2f(x);
#else
    return exp2f(x);
#endif
}

// async global->LDS, 16 B per lane, dest = wave-uniform base + lane*16
__device__ __forceinline__ void async_cp16(const void* g, void* l) {
    __builtin_amdgcn_global_load_lds(
        (const __attribute__((address_space(1))) unsigned int*)g,
        (__attribute__((address_space(3))) unsigned int*)l, 16, 0, 0);
}

// ---------------------------------------------------------------------------
// Projections (unchanged from round 1): q,k -> bf16 [B][T][H]; v -> vt[B][H][T]
// ---------------------------------------------------------------------------
__global__ __launch_bounds__(256) void proj_kernel(
    const float* __restrict__ x, const float* __restrict__ Wk,
    const float* __restrict__ Wq, const float* __restrict__ Wv,
    unsigned short* __restrict__ qo, unsigned short* __restrict__ ko,
    unsigned short* __restrict__ vto)
{
    __shared__ __align__(16) char smem[48 * 1024];
    float* xl = (float*)smem;                                  // [64][64] fp32 x tile
    float* wl = (float*)(smem + 16384);                        // [64][128] fp32 W
    unsigned short* vtl = (unsigned short*)(smem + 16384);     // [128][VS] bf16 (aliases wl)

    const int tid = threadIdx.x;
    const int b   = blockIdx.x >> 6;
    const int t0  = (blockIdx.x & 63) * 64;

    #pragma unroll
    for (int it = 0; it < 4; ++it) {
        int r = (tid >> 4) + it * 16;
        int c = (tid & 15) * 4;
        *(float4*)&xl[r * 64 + c] =
            *(const float4*)(x + ((size_t)(b * T_ + t0 + r)) * C_ + c);
    }

    const int h0 = (tid & 31) * 4;
    const int rg = tid >> 5;

    for (int m = 0; m < 3; ++m) {
        const float* W = (m == 0) ? Wk : (m == 1) ? Wq : Wv;
        __syncthreads();
        #pragma unroll
        for (int it = 0; it < 8; ++it) {
            int r = (tid >> 5) + it * 8;
            int c = (tid & 31) * 4;
            *(float4*)&wl[r * 128 + c] = *(const float4*)(W + r * 128 + c);
        }
        __syncthreads();

        float acc[8][4];
        #pragma unroll
        for (int i = 0; i < 8; ++i)
            #pragma unroll
            for (int j = 0; j < 4; ++j) acc[i][j] = 0.f;

        #pragma unroll 8
        for (int c = 0; c < 64; ++c) {
            float4 w = *(const float4*)&wl[c * 128 + h0];
            #pragma unroll
            for (int i = 0; i < 8; ++i) {
                float xi = xl[(rg * 8 + i) * 64 + c];
                acc[i][0] += xi * w.x;
                acc[i][1] += xi * w.y;
                acc[i][2] += xi * w.z;
                acc[i][3] += xi * w.w;
            }
        }

        if (m < 2) {
            unsigned short* o = (m == 0) ? ko : qo;
            #pragma unroll
            for (int i = 0; i < 8; ++i) {
                ushort4 pk;
                pk.x = f2bf(acc[i][0]); pk.y = f2bf(acc[i][1]);
                pk.z = f2bf(acc[i][2]); pk.w = f2bf(acc[i][3]);
                *(ushort4*)(o + ((size_t)(b * T_ + t0 + rg * 8 + i)) * H_ + h0) = pk;
            }
        } else {
            __syncthreads();
            #pragma unroll
            for (int i = 0; i < 8; ++i)
                #pragma unroll
                for (int c2 = 0; c2 < 4; ++c2)
                    vtl[(h0 + c2) * VS + rg * 8 + i] = f2bf(acc[i][c2]);
            __syncthreads();
            int h  = tid >> 1;
            int sg = (tid & 1) * 32;
            int4* dst = (int4*)(vto + ((size_t)(b * H_ + h)) * T_ + t0 + sg);
            const int4* src = (const int4*)&vtl[h * VS + sg];
            dst[0] = src[0]; dst[1] = src[1]; dst[2] = src[2]; dst[3] = src[3];
        }
    }
}

// ---------------------------------------------------------------------------
// Flash attention, transposed-S formulation. Block = 4 waves, BQ=128, BK=64.
// St = K·Q^T  (A=K-frag, B=Q-frag) -> C-layout regs run along s -> P written
// as packed b64 into a wave-PRIVATE swizzled region (no barrier needed).
// Vt double-buffered, staged async via global_load_lds (XOR-granule swizzle,
// unpadded 128B rows). K prefetched to VGPRs after QK. 2 barriers/chunk.
// s-split over blockIdx.z; partial O + row-sums merged by combine_kernel.
// ---------------------------------------------------------------------------
__global__ __launch_bounds__(256, 2) void attn_kernel(
    const unsigned short* __restrict__ q,
    const unsigned short* __restrict__ k,
    const unsigned short* __restrict__ vt,
    float* __restrict__ O0, float* __restrict__ O1,
    float* __restrict__ Ls, int nsplit)
{
    __shared__ __align__(16) unsigned short Kl[64 * KLS];      // 17408 B
    __shared__ __align__(16) unsigned short Vtl[2][128 * 64];  // 32768 B (swizzled)
    __shared__ __align__(16) unsigned short Pl[4 * 32 * 64];   // 16384 B (wave-private, swizzled)

    const int tid  = threadIdx.x;
    const int wave = tid >> 6;
    const int lane = tid & 63;
    const int col  = lane & 15;
    const int quad = lane >> 4;
    const int b    = blockIdx.y;
    const int q0   = blockIdx.x * BQ;
    const int split  = blockIdx.z;
    const int NC     = T_ / BK / nsplit;
    const int s_base = split * (T_ / nsplit);

    const int krow = tid >> 4;          // K staging: row (+16*it)
    const int kcol = (tid & 15) * 8;    // K staging: col (shorts)
    const int vrow = lane >> 3;         // Vt staging: row-in-call 0..7
    const int vswz = (lane & 7) ^ vrow; // Vt staging: swizzled global granule

    // Q fragments (reused NC chunks) — operand layout [idx=lane&15][k=quad*8+j]
    short8 qf[2][4];
    #pragma unroll
    for (int qt = 0; qt < 2; ++qt) {
        const unsigned short* qrow =
            q + ((size_t)(b * T_ + q0 + wave * 32 + qt * 16 + col)) * H_ + quad * 8;
        #pragma unroll
        for (int ks = 0; ks < 4; ++ks)
            qf[qt][ks] = *(const short8*)(qrow + ks * 32);
    }

    floatx4 o[2][8];
    #pragma unroll
    for (int qt = 0; qt < 2; ++qt)
        #pragma unroll
        for (int ht = 0; ht < 8; ++ht) { o[qt][ht][0]=0.f; o[qt][ht][1]=0.f; o[qt][ht][2]=0.f; o[qt][ht][3]=0.f; }
    float lsum[2] = {0.f, 0.f};

    const float SC = 0.125f * 1.44269504088896340736f;  // scale * log2(e)
    unsigned short* Pw = &Pl[wave * 32 * 64];

    int4 kr[4];
    #define LOAD_KR(S0)                                                           \
        do { _Pragma("unroll")                                                    \
            for (int it = 0; it < 4; ++it)                                        \
                kr[it] = *(const int4*)(k + ((size_t)(b * T_ + (S0) + krow + it * 16)) * H_ + kcol); \
        } while (0)

    #define ISSUE_VT(S0, BUF)                                                     \
        do { _Pragma("unroll")                                                    \
            for (int it = 0; it < 4; ++it) {                                      \
                int hbase = wave * 32 + it * 8;                                   \
                async_cp16(vt + ((size_t)(b * H_ + hbase + vrow)) * T_ + (S0) + vswz * 8, \
                           (void*)&Vtl[BUF][hbase * 64]);                         \
            }                                                                     \
        } while (0)

    LOAD_KR(s_base);
    ISSUE_VT(s_base, 0);

    for (int ci = 0; ci < NC; ++ci) {
        const int buf = ci & 1;
        // stage K chunk from prefetch regs (waits vmcnt -> also drains Vt(ci))
        #pragma unroll
        for (int it = 0; it < 4; ++it)
            *(int4*)&Kl[(krow + it * 16) * KLS + kcol] = kr[it];
        __syncthreads();                       // α: K + Vt(ci) visible
        if (ci + 1 < NC) ISSUE_VT(s_base + (ci + 1) * BK, buf ^ 1);

        // St = K·Q^T : rows=s (4 st-tiles), cols=q (2 qt-tiles), K-dim=128
        floatx4 s[2][4];
        #pragma unroll
        for (int qt = 0; qt < 2; ++qt)
            #pragma unroll
            for (int st = 0; st < 4; ++st) { s[qt][st][0]=0.f; s[qt][st][1]=0.f; s[qt][st][2]=0.f; s[qt][st][3]=0.f; }
        #pragma unroll
        for (int ks = 0; ks < 4; ++ks) {
            #pragma unroll
            for (int st = 0; st < 4; ++st) {
                short8 kf = *(const short8*)&Kl[(st * 16 + col) * KLS + ks * 32 + quad * 8];
                s[0][st] = __builtin_amdgcn_mfma_f32_16x16x32_bf16(kf, qf[0][ks], s[0][st], 0, 0, 0);
                s[1][st] = __builtin_amdgcn_mfma_f32_16x16x32_bf16(kf, qf[1][ks], s[1][st], 0, 0, 0);
            }
        }
        if (ci + 1 < NC) LOAD_KR(s_base + (ci + 1) * BK);   // prefetch next K

        // P = exp2(St*SC): lane holds 4 consecutive s for q = qt*16+col
        // -> one b64 per (qt,st) into wave-private swizzled Pw[q][s]
        #pragma unroll
        for (int qt = 0; qt < 2; ++qt) {
            const int qw = qt * 16 + col;
            #pragma unroll
            for (int st = 0; st < 4; ++st) {
                float p0 = fexp2(s[qt][st][0] * SC);
                float p1 = fexp2(s[qt][st][1] * SC);
                float p2 = fexp2(s[qt][st][2] * SC);
                float p3 = fexp2(s[qt][st][3] * SC);
                lsum[qt] += (p0 + p1) + (p2 + p3);
                int grs = (st * 2 + (quad >> 1)) ^ (qw & 7);
                *(uint2*)&Pw[qw * 64 + grs * 8 + (quad & 1) * 4] =
                    uint2{pk2bf(p0, p1), pk2bf(p2, p3)};
            }
        }

        // O += P·V  (Pw wave-private; same-wave DS ordering suffices)
        #pragma unroll
        for (int ks = 0; ks < 2; ++ks) {
            short8 pf[2];
            #pragma unroll
            for (int qt = 0; qt < 2; ++qt) {
                int qw = qt * 16 + col;
                int gf = (ks * 4 + quad) ^ (qw & 7);
                pf[qt] = *(const short8*)&Pw[qw * 64 + gf * 8];
            }
            #pragma unroll
            for (int ht = 0; ht < 8; ++ht) {
                int h  = ht * 16 + col;
                int gv = (ks * 4 + quad) ^ (h & 7);
                short8 vf = *(const short8*)&Vtl[buf][h * 64 + gv * 8];
                o[0][ht] = __builtin_amdgcn_mfma_f32_16x16x32_bf16(pf[0], vf, o[0][ht], 0, 0, 0);
                o[1][ht] = __builtin_amdgcn_mfma_f32_16x16x32_bf16(pf[1], vf, o[1][ht], 0, 0, 0);
            }
        }
        __syncthreads();                       // β: K reads done; Vt(ci+1) mostly drained
    }
    #undef LOAD_KR
    #undef ISSUE_VT

    // epilogue: reduce lsum across quads (q = qt*16+col per lane), store
    // UNNORMALIZED O + row sums; combine_kernel normalizes.
    float* Op = (split == 0) ? O0 : O1;
    #pragma unroll
    for (int qt = 0; qt < 2; ++qt) {
        float l = lsum[qt];
        l += __shfl_xor(l, 16);
        l += __shfl_xor(l, 32);
        if (quad == 0)
            Ls[(size_t)split * (B_ * T_) + b * T_ + q0 + wave * 32 + qt * 16 + col] = l;
        #pragma unroll
        for (int r = 0; r < 4; ++r) {
            int row = q0 + wave * 32 + qt * 16 + quad * 4 + r;
            float* orow = Op + ((size_t)(b * T_ + row)) * H_;
            #pragma unroll
            for (int ht = 0; ht < 8; ++ht)
                orow[ht * 16 + col] = o[qt][ht][r];
        }
    }
}

// ---------------------------------------------------------------------------
// Merge s-split partials and normalize: out = (O0 [+ O1]) / (l0 [+ l1])
// ---------------------------------------------------------------------------
__global__ __launch_bounds__(256) void combine_kernel(
    float* __restrict__ out, const float* __restrict__ O1,
    const float* __restrict__ Ls, int nsplit)
{
    int i = blockIdx.x * 256 + threadIdx.x;   // float4 index, H/4 = 32 per row
    int row = i >> 5;
    float4 a = ((const float4*)out)[i];
    float l = Ls[row];
    if (nsplit == 2) {
        float4 c = ((const float4*)O1)[i];
        a.x += c.x; a.y += c.y; a.z += c.z; a.w += c.w;
        l += Ls[B_ * T_ + row];
    }
    float rinv = 1.0f / l;
    a.x *= rinv; a.y *= rinv; a.z *= rinv; a.w *= rinv;
    ((float4*)out)[i] = a;
}

extern "C" void kernel_launch(void* const* d_in, const int* in_sizes, int n_in,
                              void* d_out, int out_size, void* d_ws, size_t ws_size,
                              hipStream_t stream)
{
    const float* x  = (const float*)d_in[0];
    const float* Wk = (const float*)d_in[1];
    const float* Wq = (const float*)d_in[2];
    const float* Wv = (const float*)d_in[3];
    float* out = (float*)d_out;

    const size_t elems = (size_t)B_ * T_ * H_;            // 8.4M elements
    unsigned short* qb  = (unsigned short*)d_ws;          // bf16 q   [B][T][H]  16 MB
    unsigned short* kb  = qb + elems;                     // bf16 k   [B][T][H]  16 MB
    unsigned short* vtb = kb + elems;                     // bf16 v^T [B][H][T]  16 MB
    float* Ls = (float*)(vtb + elems);                    // [2][B*T] fp32 row sums
    float* O1 = Ls + 2 * (size_t)B_ * T_;                 // split-1 O partial (fp32, 32 MB)

    const size_t need2 = 3 * elems * 2 + 2 * (size_t)B_ * T_ * 4 + elems * 4;
    const int ns = (ws_size >= need2) ? 2 : 1;

    proj_kernel<<<dim3(B_ * 64), dim3(256), 0, stream>>>(x, Wk, Wq, Wv, qb, kb, vtb);
    attn_kernel<<<dim3(T_ / BQ, B_, ns), dim3(256), 0, stream>>>(qb, kb, vtb, out, O1, Ls, ns);
    combine_kernel<<<dim3((int)(elems / 4 / 256)), dim3(256), 0, stream>>>(out, O1, Ls, ns);
}